// Round 8
// baseline (560.199 us; speedup 1.0000x reference)
//
#include <hip/hip_runtime.h>
#include <math.h>

#define NN 50000
#define NE 800000
#define CH 64
#define SCAN_BLK 1024
#define NB1 ((NN + SCAN_BLK - 1) / SCAN_BLK)  // 49
#define LDA 129  // LDS row stride: 129 mod 32 = 1 -> micro-tile rows land on
                 // distinct bank quads (2-way max aliasing = free, m136)

typedef float v4f __attribute__((ext_vector_type(4)));

// ---------------- counting-sort pipeline (atomic-free aggregation) ----------

// 1) histogram of dst
__global__ __launch_bounds__(256) void hist_k(const int* __restrict__ ei,
                                              int* __restrict__ count) {
    int i = blockIdx.x * 256 + threadIdx.x;
    const int stride = gridDim.x * 256;
    for (int e = i; e < NE; e += stride)
        atomicAdd(&count[ei[NE + e]], 1);
}

// 2a) per-block (1024-elem) local exclusive scan + block total
__global__ __launch_bounds__(256) void scan1_k(const int* __restrict__ count,
                                               int* __restrict__ start,
                                               int* __restrict__ blockSum) {
    __shared__ int lds[256];
    const int t = threadIdx.x;
    const int base = blockIdx.x * SCAN_BLK + t * 4;
    int c0 = 0, c1 = 0, c2 = 0, c3 = 0;
    if (base + 3 < NN) {
        int4 v = *(const int4*)(count + base);
        c0 = v.x; c1 = v.y; c2 = v.z; c3 = v.w;
    } else {
        if (base + 0 < NN) c0 = count[base + 0];
        if (base + 1 < NN) c1 = count[base + 1];
        if (base + 2 < NN) c2 = count[base + 2];
    }
    const int tsum = c0 + c1 + c2 + c3;
    lds[t] = tsum;
    __syncthreads();
    for (int off = 1; off < 256; off <<= 1) {
        int add = (t >= off) ? lds[t - off] : 0;
        __syncthreads();
        lds[t] += add;
        __syncthreads();
    }
    if (t == 255) blockSum[blockIdx.x] = lds[255];
    int r = lds[t] - tsum;  // thread-exclusive base within block
    if (base + 0 < NN) start[base + 0] = r; r += c0;
    if (base + 1 < NN) start[base + 1] = r; r += c1;
    if (base + 2 < NN) start[base + 2] = r; r += c2;
    if (base + 3 < NN) start[base + 3] = r;
}

// 2b) single-wave scan of the 49 block sums
__global__ __launch_bounds__(64) void scan2_k(const int* __restrict__ blockSum,
                                              int* __restrict__ blockOff,
                                              int* __restrict__ start) {
    const int t = threadIdx.x;
    const int orig = (t < NB1) ? blockSum[t] : 0;
    int v = orig;
    for (int off = 1; off < 64; off <<= 1) {
        int n = __shfl_up(v, off, 64);
        if (t >= off) v += n;
    }
    if (t < NB1) blockOff[t] = v - orig;   // exclusive
    if (t == NB1 - 1) start[NN] = v;       // total == NE
}

// 2c) add block offsets; materialize cursor
__global__ __launch_bounds__(256) void scan3_k(int* __restrict__ start,
                                               int* __restrict__ cursor,
                                               const int* __restrict__ blockOff) {
    const int t = threadIdx.x;
    const int base = blockIdx.x * SCAN_BLK + t * 4;
    const int off = blockOff[blockIdx.x];
    if (base + 3 < NN) {
        int4 v = *(const int4*)(start + base);
        v.x += off; v.y += off; v.z += off; v.w += off;
        *(int4*)(start + base) = v;
        *(int4*)(cursor + base) = v;
    } else {
        for (int k = 0; k < 4; ++k)
            if (base + k < NN) {
                int v = start[base + k] + off;
                start[base + k] = v;
                cursor[base + k] = v;
            }
    }
}

// 3) place packed (src, norm) into dst-sorted order — one 8B store per edge
__global__ __launch_bounds__(256) void place_k(const int* __restrict__ ei,
                                               const float* __restrict__ ea,
                                               int* __restrict__ cursor,
                                               int2* __restrict__ pp) {
    int i = blockIdx.x * 256 + threadIdx.x;
    const int stride = gridDim.x * 256;
    for (int e = i; e < NE; e += stride) {
        const int src = ei[e];
        const int dst = ei[NE + e];
        const float a0 = ea[3 * e + 0];
        const float a1 = ea[3 * e + 1];
        const float a2 = ea[3 * e + 2];
        const float nrm = sqrtf(a0 * a0 + a1 * a1 + a2 * a2);
        const int pos = atomicAdd(&cursor[dst], 1);
        int2 pr; pr.x = src; pr.y = __float_as_int(nrm);
        pp[pos] = pr;
    }
}

// 4) per-node register accumulation: s[n,c] = sum_{e in seg(n)} nrm_e * x[src_e, c]
//    One wave per node, lane = channel; 8-deep unrolled gathers. Zero f32 atomics.
__global__ __launch_bounds__(256) void agg_k(const float* __restrict__ x,
                                             const int* __restrict__ start,
                                             const int2* __restrict__ pp,
                                             float* __restrict__ s) {
    const int c = threadIdx.x & 63;
    int w = (int)((blockIdx.x * 256u + threadIdx.x) >> 6);
    const int nw = (int)((gridDim.x * 256u) >> 6);
    for (int n = w; n < NN; n += nw) {
        const int b = start[n];
        const int e = start[n + 1];
        float acc0 = 0.f, acc1 = 0.f;
        int j = b;
        for (; j + 8 <= e; j += 8) {
            const int2 p0 = pp[j],     p1 = pp[j + 1], p2 = pp[j + 2], p3 = pp[j + 3];
            const int2 p4 = pp[j + 4], p5 = pp[j + 5], p6 = pp[j + 6], p7 = pp[j + 7];
            const float x0 = x[(size_t)p0.x * CH + c];
            const float x1 = x[(size_t)p1.x * CH + c];
            const float x2 = x[(size_t)p2.x * CH + c];
            const float x3 = x[(size_t)p3.x * CH + c];
            const float x4 = x[(size_t)p4.x * CH + c];
            const float x5 = x[(size_t)p5.x * CH + c];
            const float x6 = x[(size_t)p6.x * CH + c];
            const float x7 = x[(size_t)p7.x * CH + c];
            acc0 = fmaf(__int_as_float(p0.y), x0, acc0);
            acc1 = fmaf(__int_as_float(p1.y), x1, acc1);
            acc0 = fmaf(__int_as_float(p2.y), x2, acc0);
            acc1 = fmaf(__int_as_float(p3.y), x3, acc1);
            acc0 = fmaf(__int_as_float(p4.y), x4, acc0);
            acc1 = fmaf(__int_as_float(p5.y), x5, acc1);
            acc0 = fmaf(__int_as_float(p6.y), x6, acc0);
            acc1 = fmaf(__int_as_float(p7.y), x7, acc1);
        }
        for (; j < e; ++j) {
            const int2 p = pp[j];
            acc0 = fmaf(__int_as_float(p.y), x[(size_t)p.x * CH + c], acc0);
        }
        s[(size_t)n * CH + c] = acc0 + acc1;
    }
}

// ---------------- fallback scatter (round-2 proven, atomic-rate bound) ------
__global__ __launch_bounds__(256) void scatter_r2(const float* __restrict__ x,
                                                  const int* __restrict__ ei,
                                                  const float* __restrict__ ea,
                                                  float* s) {
    const int lane = threadIdx.x & 63;
    int w = (int)((blockIdx.x * 256u + threadIdx.x) >> 6);
    const int nw = (int)((gridDim.x * 256u) >> 6);
    for (int e = w; e < NE; e += nw) {
        const int src = ei[e];
        const int dst = ei[NE + e];
        const float a0 = ea[3 * e + 0];
        const float a1 = ea[3 * e + 1];
        const float a2 = ea[3 * e + 2];
        const float nrm = sqrtf(a0 * a0 + a1 * a1 + a2 * a2);
        atomicAdd(&s[(size_t)dst * CH + lane], nrm * x[(size_t)src * CH + lane]);
    }
}

// ---------------- epilogue as LDS-tiled GEMM --------------------------------
// out[64-row tile] = [x|s](64x128) . [psi|phi]^T(64x128)
// r5-r7 lesson: per-lane weights-in-registers needs 128 VGPR of invariant
// loads; the allocator remats/spills them regardless of launch_bounds or asm
// pins (VGPR stuck at 84/104). LDS tiling has an allocator-independent cost:
// per 4-K chunk, 8 ds_read_b128 feed 64 FMAs -> ~37.5k LDS cyc/CU ~ 16 us.
// Row stride 129 (mod 32 = 1): A-reads hit 8 bank-quads 2-way (free); B-reads
// same; 16-lane same-address groups are broadcasts. LDS 2*64*129*4 = 64.5KB
// -> 2 blocks/CU. s may alias out: tile fully staged into LDS before stores,
// blocks own disjoint row ranges -> race-free.
__global__ __launch_bounds__(256) void out_gemm_k(const float* __restrict__ x,
                                                  const float* s,
                                                  const float* __restrict__ phi,
                                                  const float* __restrict__ psi,
                                                  float* out) {
    __shared__ float A[64][LDA];  // [row][ 0..63 = x, 64..127 = s ]
    __shared__ float B[64][LDA];  // [o]  [ 0..63 = psi, 64..127 = phi ]
    const int t = threadIdx.x;
    const int n0 = blockIdx.x * 64;

    // stage B (weights): 64 rows x 16 f4 per matrix; 4 f4-chunks per thread
    for (int idx = t; idx < 64 * 16; idx += 256) {
        const int o = idx >> 4, j = idx & 15;
        v4f p = *(const v4f*)(psi + (size_t)o * CH + 4 * j);
        v4f q = *(const v4f*)(phi + (size_t)o * CH + 4 * j);
        *(v4f*)&B[o][4 * j] = p;
        *(v4f*)&B[o][64 + 4 * j] = q;
    }
    // stage A (rows), zero-padded past NN
    for (int idx = t; idx < 64 * 16; idx += 256) {
        const int r = idx >> 4, j = idx & 15;
        const int n = n0 + r;
        v4f xv = {0.f, 0.f, 0.f, 0.f}, sv = {0.f, 0.f, 0.f, 0.f};
        if (n < NN) {
            xv = *(const v4f*)(x + (size_t)n * CH + 4 * j);
            sv = *(const v4f*)(s + (size_t)n * CH + 4 * j);
        }
        *(v4f*)&A[r][4 * j] = xv;
        *(v4f*)&A[r][64 + 4 * j] = sv;
    }
    __syncthreads();

    // 4x4 micro-tile: thread (tr = t>>4, tc = t&15) -> rows 4tr.., cols 4tc..
    const int r0 = (t >> 4) * 4;
    const int c0 = (t & 15) * 4;
    float acc[4][4] = {{0.f}};
#pragma unroll
    for (int i = 0; i < 128; i += 4) {
        v4f a0 = *(const v4f*)&A[r0 + 0][i];
        v4f a1 = *(const v4f*)&A[r0 + 1][i];
        v4f a2 = *(const v4f*)&A[r0 + 2][i];
        v4f a3 = *(const v4f*)&A[r0 + 3][i];
        v4f b0 = *(const v4f*)&B[c0 + 0][i];
        v4f b1 = *(const v4f*)&B[c0 + 1][i];
        v4f b2 = *(const v4f*)&B[c0 + 2][i];
        v4f b3 = *(const v4f*)&B[c0 + 3][i];
#define FMA4(k, av)                                   \
        acc[k][0] = fmaf(av.x, b0.x, acc[k][0]);      \
        acc[k][0] = fmaf(av.y, b0.y, acc[k][0]);      \
        acc[k][0] = fmaf(av.z, b0.z, acc[k][0]);      \
        acc[k][0] = fmaf(av.w, b0.w, acc[k][0]);      \
        acc[k][1] = fmaf(av.x, b1.x, acc[k][1]);      \
        acc[k][1] = fmaf(av.y, b1.y, acc[k][1]);      \
        acc[k][1] = fmaf(av.z, b1.z, acc[k][1]);      \
        acc[k][1] = fmaf(av.w, b1.w, acc[k][1]);      \
        acc[k][2] = fmaf(av.x, b2.x, acc[k][2]);      \
        acc[k][2] = fmaf(av.y, b2.y, acc[k][2]);      \
        acc[k][2] = fmaf(av.z, b2.z, acc[k][2]);      \
        acc[k][2] = fmaf(av.w, b2.w, acc[k][2]);      \
        acc[k][3] = fmaf(av.x, b3.x, acc[k][3]);      \
        acc[k][3] = fmaf(av.y, b3.y, acc[k][3]);      \
        acc[k][3] = fmaf(av.z, b3.z, acc[k][3]);      \
        acc[k][3] = fmaf(av.w, b3.w, acc[k][3])
        FMA4(0, a0);
        FMA4(1, a1);
        FMA4(2, a2);
        FMA4(3, a3);
#undef FMA4
    }

#pragma unroll
    for (int k = 0; k < 4; ++k) {
        const int n = n0 + r0 + k;
        if (n < NN) {
            v4f v; v.x = acc[k][0]; v.y = acc[k][1]; v.z = acc[k][2]; v.w = acc[k][3];
            *(v4f*)(out + (size_t)n * CH + c0) = v;
        }
    }
}

extern "C" void kernel_launch(void* const* d_in, const int* in_sizes, int n_in,
                              void* d_out, int out_size, void* d_ws, size_t ws_size,
                              hipStream_t stream) {
    const float* x   = (const float*)d_in[0];
    const int*   ei  = (const int*)d_in[1];
    const float* ea  = (const float*)d_in[2];
    const float* phi = (const float*)d_in[3];
    const float* psi = (const float*)d_in[4];
    float* out = (float*)d_out;

    // ws layout (8B-aligned first): pair[NE] | count[NN] | start[NN+1] |
    //                               cursor[NN] | blockSum[64] | blockOff[64]
    const size_t need = (size_t)NE * 8 + ((size_t)NN + (NN + 1) + NN + 128) * 4;
    const int ngemm = (NN + 63) / 64;  // 782

    if (ws_size >= need) {
        int2* pp    = (int2*)d_ws;
        int* count  = (int*)(pp + NE);
        int* start  = count + NN;
        int* cursor = start + (NN + 1);
        int* blockSum = cursor + NN;
        int* blockOff = blockSum + 64;

        (void)hipMemsetAsync(count, 0, (size_t)NN * sizeof(int), stream);
        hist_k<<<1024, 256, 0, stream>>>(ei, count);
        scan1_k<<<NB1, 256, 0, stream>>>(count, start, blockSum);
        scan2_k<<<1, 64, 0, stream>>>(blockSum, blockOff, start);
        scan3_k<<<NB1, 256, 0, stream>>>(start, cursor, blockOff);
        place_k<<<1024, 256, 0, stream>>>(ei, ea, cursor, pp);
        agg_k<<<2048, 256, 0, stream>>>(x, start, pp, out);  // s lives in out
        out_gemm_k<<<ngemm, 256, 0, stream>>>(x, out, phi, psi, out);
    } else {
        // fallback: proven round-2 path (atomic-rate bound)
        (void)hipMemsetAsync(out, 0, (size_t)NN * CH * sizeof(float), stream);
        scatter_r2<<<4096, 256, 0, stream>>>(x, ei, ea, out);
        out_gemm_k<<<ngemm, 256, 0, stream>>>(x, out, phi, psi, out);
    }
}

// Round 9
// 231.293 us; speedup vs baseline: 2.4220x; 2.4220x over previous
//
#include <hip/hip_runtime.h>
#include <math.h>

#define NN 50000
#define NE 800000
#define CH 64
#define SCAN_BLK 1024
#define NB1 ((NN + SCAN_BLK - 1) / SCAN_BLK)  // 49
#define LDA 129  // LDS row stride: quad-stride 129/4 -> (129k+i/4) mod 8 spreads
                 // 16 lanes over 8 bank-quads 2-way (free, m136)

typedef float v4f __attribute__((ext_vector_type(4)));

// ---------------- counting-sort pipeline (atomic-free aggregation) ----------

// 1) histogram of dst
__global__ __launch_bounds__(256) void hist_k(const int* __restrict__ ei,
                                              int* __restrict__ count) {
    int i = blockIdx.x * 256 + threadIdx.x;
    const int stride = gridDim.x * 256;
    for (int e = i; e < NE; e += stride)
        atomicAdd(&count[ei[NE + e]], 1);
}

// 2a) per-block (1024-elem) local exclusive scan + block total
__global__ __launch_bounds__(256) void scan1_k(const int* __restrict__ count,
                                               int* __restrict__ start,
                                               int* __restrict__ blockSum) {
    __shared__ int lds[256];
    const int t = threadIdx.x;
    const int base = blockIdx.x * SCAN_BLK + t * 4;
    int c0 = 0, c1 = 0, c2 = 0, c3 = 0;
    if (base + 3 < NN) {
        int4 v = *(const int4*)(count + base);
        c0 = v.x; c1 = v.y; c2 = v.z; c3 = v.w;
    } else {
        if (base + 0 < NN) c0 = count[base + 0];
        if (base + 1 < NN) c1 = count[base + 1];
        if (base + 2 < NN) c2 = count[base + 2];
    }
    const int tsum = c0 + c1 + c2 + c3;
    lds[t] = tsum;
    __syncthreads();
    for (int off = 1; off < 256; off <<= 1) {
        int add = (t >= off) ? lds[t - off] : 0;
        __syncthreads();
        lds[t] += add;
        __syncthreads();
    }
    if (t == 255) blockSum[blockIdx.x] = lds[255];
    int r = lds[t] - tsum;  // thread-exclusive base within block
    if (base + 0 < NN) start[base + 0] = r; r += c0;
    if (base + 1 < NN) start[base + 1] = r; r += c1;
    if (base + 2 < NN) start[base + 2] = r; r += c2;
    if (base + 3 < NN) start[base + 3] = r;
}

// 2b) single-wave scan of the 49 block sums
__global__ __launch_bounds__(64) void scan2_k(const int* __restrict__ blockSum,
                                              int* __restrict__ blockOff,
                                              int* __restrict__ start) {
    const int t = threadIdx.x;
    const int orig = (t < NB1) ? blockSum[t] : 0;
    int v = orig;
    for (int off = 1; off < 64; off <<= 1) {
        int n = __shfl_up(v, off, 64);
        if (t >= off) v += n;
    }
    if (t < NB1) blockOff[t] = v - orig;   // exclusive
    if (t == NB1 - 1) start[NN] = v;       // total == NE
}

// 2c) add block offsets; materialize cursor
__global__ __launch_bounds__(256) void scan3_k(int* __restrict__ start,
                                               int* __restrict__ cursor,
                                               const int* __restrict__ blockOff) {
    const int t = threadIdx.x;
    const int base = blockIdx.x * SCAN_BLK + t * 4;
    const int off = blockOff[blockIdx.x];
    if (base + 3 < NN) {
        int4 v = *(const int4*)(start + base);
        v.x += off; v.y += off; v.z += off; v.w += off;
        *(int4*)(start + base) = v;
        *(int4*)(cursor + base) = v;
    } else {
        for (int k = 0; k < 4; ++k)
            if (base + k < NN) {
                int v = start[base + k] + off;
                start[base + k] = v;
                cursor[base + k] = v;
            }
    }
}

// 3) place packed (src, norm) into dst-sorted order — one 8B store per edge
__global__ __launch_bounds__(256) void place_k(const int* __restrict__ ei,
                                               const float* __restrict__ ea,
                                               int* __restrict__ cursor,
                                               int2* __restrict__ pp) {
    int i = blockIdx.x * 256 + threadIdx.x;
    const int stride = gridDim.x * 256;
    for (int e = i; e < NE; e += stride) {
        const int src = ei[e];
        const int dst = ei[NE + e];
        const float a0 = ea[3 * e + 0];
        const float a1 = ea[3 * e + 1];
        const float a2 = ea[3 * e + 2];
        const float nrm = sqrtf(a0 * a0 + a1 * a1 + a2 * a2);
        const int pos = atomicAdd(&cursor[dst], 1);
        int2 pr; pr.x = src; pr.y = __float_as_int(nrm);
        pp[pos] = pr;
    }
}

// 4) per-node register accumulation: s[n,c] = sum_{e in seg(n)} nrm_e * x[src_e, c]
//    One wave per node, lane = channel; 8-deep unrolled gathers. Zero f32 atomics.
__global__ __launch_bounds__(256) void agg_k(const float* __restrict__ x,
                                             const int* __restrict__ start,
                                             const int2* __restrict__ pp,
                                             float* __restrict__ s) {
    const int c = threadIdx.x & 63;
    int w = (int)((blockIdx.x * 256u + threadIdx.x) >> 6);
    const int nw = (int)((gridDim.x * 256u) >> 6);
    for (int n = w; n < NN; n += nw) {
        const int b = start[n];
        const int e = start[n + 1];
        float acc0 = 0.f, acc1 = 0.f;
        int j = b;
        for (; j + 8 <= e; j += 8) {
            const int2 p0 = pp[j],     p1 = pp[j + 1], p2 = pp[j + 2], p3 = pp[j + 3];
            const int2 p4 = pp[j + 4], p5 = pp[j + 5], p6 = pp[j + 6], p7 = pp[j + 7];
            const float x0 = x[(size_t)p0.x * CH + c];
            const float x1 = x[(size_t)p1.x * CH + c];
            const float x2 = x[(size_t)p2.x * CH + c];
            const float x3 = x[(size_t)p3.x * CH + c];
            const float x4 = x[(size_t)p4.x * CH + c];
            const float x5 = x[(size_t)p5.x * CH + c];
            const float x6 = x[(size_t)p6.x * CH + c];
            const float x7 = x[(size_t)p7.x * CH + c];
            acc0 = fmaf(__int_as_float(p0.y), x0, acc0);
            acc1 = fmaf(__int_as_float(p1.y), x1, acc1);
            acc0 = fmaf(__int_as_float(p2.y), x2, acc0);
            acc1 = fmaf(__int_as_float(p3.y), x3, acc1);
            acc0 = fmaf(__int_as_float(p4.y), x4, acc0);
            acc1 = fmaf(__int_as_float(p5.y), x5, acc1);
            acc0 = fmaf(__int_as_float(p6.y), x6, acc0);
            acc1 = fmaf(__int_as_float(p7.y), x7, acc1);
        }
        for (; j < e; ++j) {
            const int2 p = pp[j];
            acc0 = fmaf(__int_as_float(p.y), x[(size_t)p.x * CH + c], acc0);
        }
        s[(size_t)n * CH + c] = acc0 + acc1;
    }
}

// ---------------- fallback scatter (round-2 proven, atomic-rate bound) ------
__global__ __launch_bounds__(256) void scatter_r2(const float* __restrict__ x,
                                                  const int* __restrict__ ei,
                                                  const float* __restrict__ ea,
                                                  float* s) {
    const int lane = threadIdx.x & 63;
    int w = (int)((blockIdx.x * 256u + threadIdx.x) >> 6);
    const int nw = (int)((gridDim.x * 256u) >> 6);
    for (int e = w; e < NE; e += nw) {
        const int src = ei[e];
        const int dst = ei[NE + e];
        const float a0 = ea[3 * e + 0];
        const float a1 = ea[3 * e + 1];
        const float a2 = ea[3 * e + 2];
        const float nrm = sqrtf(a0 * a0 + a1 * a1 + a2 * a2);
        atomicAdd(&s[(size_t)dst * CH + lane], nrm * x[(size_t)src * CH + lane]);
    }
}

// ---------------- epilogue as LDS-tiled GEMM --------------------------------
// out[64-row tile] = [x|s](64x128) . [psi|phi]^T(64x128)
// r8 lesson: FULL unroll of the K loop -> compiler hoists ~256 loads ->
// VGPR=256 + scratch spill (hbm_bytes 610MB, 370 µs). Fix: unroll_count(2)
// (16 live v4f = 64 regs + 16 acc ~ 95 VGPR) and __launch_bounds__(256,2)
// (cap 128 VGPR, 2 waves/SIMD; LDS 66KB -> 2 blocks/CU).
// Cost model: 1024 wave-ds_read_b128 per 64 rows -> ~3 blk/CU * 12cyc ~ 16 µs.
// s may alias out: tile fully staged into LDS before stores; blocks own
// disjoint row ranges -> race-free.
__global__ __launch_bounds__(256, 2) void out_gemm_k(const float* __restrict__ x,
                                                     const float* s,
                                                     const float* __restrict__ phi,
                                                     const float* __restrict__ psi,
                                                     float* out) {
    __shared__ float A[64][LDA];  // [row][ 0..63 = x, 64..127 = s ]
    __shared__ float B[64][LDA];  // [o]  [ 0..63 = psi, 64..127 = phi ]
    const int t = threadIdx.x;
    const int n0 = blockIdx.x * 64;

    // stage B (weights): 64 rows x 16 f4 per matrix
    for (int idx = t; idx < 64 * 16; idx += 256) {
        const int o = idx >> 4, j = idx & 15;
        v4f p = *(const v4f*)(psi + (size_t)o * CH + 4 * j);
        v4f q = *(const v4f*)(phi + (size_t)o * CH + 4 * j);
        *(v4f*)&B[o][4 * j] = p;
        *(v4f*)&B[o][64 + 4 * j] = q;
    }
    // stage A (rows), zero-padded past NN
    for (int idx = t; idx < 64 * 16; idx += 256) {
        const int r = idx >> 4, j = idx & 15;
        const int n = n0 + r;
        v4f xv = {0.f, 0.f, 0.f, 0.f}, sv = {0.f, 0.f, 0.f, 0.f};
        if (n < NN) {
            xv = *(const v4f*)(x + (size_t)n * CH + 4 * j);
            sv = *(const v4f*)(s + (size_t)n * CH + 4 * j);
        }
        *(v4f*)&A[r][4 * j] = xv;
        *(v4f*)&A[r][64 + 4 * j] = sv;
    }
    __syncthreads();

    // 4x4 micro-tile: thread (tr = t>>4, tc = t&15) -> rows 4tr.., cols 4tc..
    const int r0 = (t >> 4) * 4;
    const int c0 = (t & 15) * 4;
    float acc[4][4] = {{0.f}};
#pragma clang loop unroll_count(2)
    for (int i = 0; i < 128; i += 4) {
        v4f a0 = *(const v4f*)&A[r0 + 0][i];
        v4f a1 = *(const v4f*)&A[r0 + 1][i];
        v4f a2 = *(const v4f*)&A[r0 + 2][i];
        v4f a3 = *(const v4f*)&A[r0 + 3][i];
        v4f b0 = *(const v4f*)&B[c0 + 0][i];
        v4f b1 = *(const v4f*)&B[c0 + 1][i];
        v4f b2 = *(const v4f*)&B[c0 + 2][i];
        v4f b3 = *(const v4f*)&B[c0 + 3][i];
#define FMA4(k, av)                                   \
        acc[k][0] = fmaf(av.x, b0.x, acc[k][0]);      \
        acc[k][0] = fmaf(av.y, b0.y, acc[k][0]);      \
        acc[k][0] = fmaf(av.z, b0.z, acc[k][0]);      \
        acc[k][0] = fmaf(av.w, b0.w, acc[k][0]);      \
        acc[k][1] = fmaf(av.x, b1.x, acc[k][1]);      \
        acc[k][1] = fmaf(av.y, b1.y, acc[k][1]);      \
        acc[k][1] = fmaf(av.z, b1.z, acc[k][1]);      \
        acc[k][1] = fmaf(av.w, b1.w, acc[k][1]);      \
        acc[k][2] = fmaf(av.x, b2.x, acc[k][2]);      \
        acc[k][2] = fmaf(av.y, b2.y, acc[k][2]);      \
        acc[k][2] = fmaf(av.z, b2.z, acc[k][2]);      \
        acc[k][2] = fmaf(av.w, b2.w, acc[k][2]);      \
        acc[k][3] = fmaf(av.x, b3.x, acc[k][3]);      \
        acc[k][3] = fmaf(av.y, b3.y, acc[k][3]);      \
        acc[k][3] = fmaf(av.z, b3.z, acc[k][3]);      \
        acc[k][3] = fmaf(av.w, b3.w, acc[k][3])
        FMA4(0, a0);
        FMA4(1, a1);
        FMA4(2, a2);
        FMA4(3, a3);
#undef FMA4
    }

#pragma unroll
    for (int k = 0; k < 4; ++k) {
        const int n = n0 + r0 + k;
        if (n < NN) {
            v4f v; v.x = acc[k][0]; v.y = acc[k][1]; v.z = acc[k][2]; v.w = acc[k][3];
            *(v4f*)(out + (size_t)n * CH + c0) = v;
        }
    }
}

extern "C" void kernel_launch(void* const* d_in, const int* in_sizes, int n_in,
                              void* d_out, int out_size, void* d_ws, size_t ws_size,
                              hipStream_t stream) {
    const float* x   = (const float*)d_in[0];
    const int*   ei  = (const int*)d_in[1];
    const float* ea  = (const float*)d_in[2];
    const float* phi = (const float*)d_in[3];
    const float* psi = (const float*)d_in[4];
    float* out = (float*)d_out;

    // ws layout (8B-aligned first): pair[NE] | count[NN] | start[NN+1] |
    //                               cursor[NN] | blockSum[64] | blockOff[64]
    const size_t need = (size_t)NE * 8 + ((size_t)NN + (NN + 1) + NN + 128) * 4;
    const int ngemm = (NN + 63) / 64;  // 782

    if (ws_size >= need) {
        int2* pp    = (int2*)d_ws;
        int* count  = (int*)(pp + NE);
        int* start  = count + NN;
        int* cursor = start + (NN + 1);
        int* blockSum = cursor + NN;
        int* blockOff = blockSum + 64;

        (void)hipMemsetAsync(count, 0, (size_t)NN * sizeof(int), stream);
        hist_k<<<1024, 256, 0, stream>>>(ei, count);
        scan1_k<<<NB1, 256, 0, stream>>>(count, start, blockSum);
        scan2_k<<<1, 64, 0, stream>>>(blockSum, blockOff, start);
        scan3_k<<<NB1, 256, 0, stream>>>(start, cursor, blockOff);
        place_k<<<1024, 256, 0, stream>>>(ei, ea, cursor, pp);
        agg_k<<<2048, 256, 0, stream>>>(x, start, pp, out);  // s lives in out
        out_gemm_k<<<ngemm, 256, 0, stream>>>(x, out, phi, psi, out);
    } else {
        // fallback: proven round-2 path (atomic-rate bound)
        (void)hipMemsetAsync(out, 0, (size_t)NN * CH * sizeof(float), stream);
        scatter_r2<<<4096, 256, 0, stream>>>(x, ei, ea, out);
        out_gemm_k<<<ngemm, 256, 0, stream>>>(x, out, phi, psi, out);
    }
}